// Round 27
// baseline (93.938 us; speedup 1.0000x reference)
//
#include <hip/hip_runtime.h>

#define B_ 2
#define S_ 8192
#define H_ 8
#define D_ 64
#define HD_ 512
#define WIN_ 512

typedef __bf16 bf16x8 __attribute__((ext_vector_type(8)));
typedef float f32x4 __attribute__((ext_vector_type(4)));
typedef unsigned short u16;
typedef unsigned int u32;

__device__ __forceinline__ u16 f2bf(float f) {
  u32 u = __float_as_uint(f);
  u += 0x7FFFu + ((u >> 16) & 1u);
  return (u16)(u >> 16);
}

__device__ __forceinline__ bf16x8 cvt8s(const float* p, float s) {
  const float4 a = *(const float4*)p;
  const float4 b = *(const float4*)(p + 4);
  union { u16 s[8]; bf16x8 v; } r;
  r.s[0] = f2bf(a.x * s); r.s[1] = f2bf(a.y * s); r.s[2] = f2bf(a.z * s); r.s[3] = f2bf(a.w * s);
  r.s[4] = f2bf(b.x * s); r.s[5] = f2bf(b.y * s); r.s[6] = f2bf(b.z * s); r.s[7] = f2bf(b.w * s);
  return r.v;
}

__device__ __forceinline__ bf16x8 cvt8(const float* p) {
  const float4 a = *(const float4*)p;
  const float4 b = *(const float4*)(p + 4);
  union { u16 s[8]; bf16x8 v; } r;
  r.s[0] = f2bf(a.x); r.s[1] = f2bf(a.y); r.s[2] = f2bf(a.z); r.s[3] = f2bf(a.w);
  r.s[4] = f2bf(b.x); r.s[5] = f2bf(b.y); r.s[6] = f2bf(b.z); r.s[7] = f2bf(b.w);
  return r.v;
}

#define MFMA(a, b, c) __builtin_amdgcn_mfma_f32_16x16x32_bf16(a, b, c, 0, 0, 0)

// ---------------------------------------------------------------------------
// Block-cooperative sliding-window flash attention, fused fp32 staging,
// BK=64 key tiles (12 barrier generations). 1024 threads = 16 waves x 16
// queries; block owns 256 q; 512 blocks = 2 resident blocks/CU. Each tile:
// one barrier, two 32-key subtiles computed back-to-back from the same
// staged buffers. Staging: tid<256 K (2 row-chunks), tid in [256,512) V
// (2 d-chunks, on-the-fly transpose). K [64k][64d], V [64d][64k], both
// with (^ (row&7)<<3) 16B-slot swizzle. P rows 40 elem. Fixed-ref exp2
// softmax; truncating P->bf16. [BEST VERIFIED: attn ~72us]
// ---------------------------------------------------------------------------
__global__ __launch_bounds__(1024, 4) void attn_kernel(const float* __restrict__ q,
                                                       const float* __restrict__ kf,
                                                       const float* __restrict__ vf,
                                                       u16* __restrict__ attn) {
  const int tid = threadIdx.x;
  const int lane = tid & 63;
  const int wave = tid >> 6;   // 0..15
  const int lg = lane >> 4;    // 0..3
  const int lj = lane & 15;    // 0..15
  // XCD swizzle: 512 blocks, 8 XCDs, 64-block contiguous chunks (bijective)
  const int bid = (int)blockIdx.x;
  const int swz = (bid & 7) * 64 + (bid >> 3);
  const int qc = swz & 31;     // S_/256 = 32 query chunks
  const int bh = swz >> 5;
  const int b = bh >> 3, h = bh & 7;
  const int q0blk = qc * 256;
  const int q0w = q0blk + wave * 16;

  __shared__ __align__(16) u16 klds0[64 * 64], klds1[64 * 64];  // 8KB each
  __shared__ __align__(16) u16 vlds0[64 * 64], vlds1[64 * 64];  // 8KB each
  __shared__ __align__(16) u16 plds[16][16 * 40];               // 1280B/wave

  const float qscale = 0.125f * 1.4426950408889634f;
  bf16x8 aq0, aq1;
  {
    const float* qrow = q + ((size_t)(b * S_ + q0w + lj) * H_ + h) * D_;
    aq0 = cvt8s(qrow + lg * 8, qscale);
    aq1 = cvt8s(qrow + 32 + lg * 8, qscale);
  }

  f32x4 o0 = {0.f, 0.f, 0.f, 0.f}, o1 = o0, o2 = o0, o3 = o0;
  float lacc[4] = {0.f, 0.f, 0.f, 0.f};

  // per-wave valid range in 32-key SUBTILE units
  const int tbw32 = (q0w >= WIN_) ? ((q0w - (WIN_ - 1)) >> 5) : 0;
  const int tew32 = (q0w + 15) >> 5;
  const bool wmask = (q0w >= WIN_);
  // block union range in 64-key TILE units
  const int tbu = (q0blk >= WIN_) ? ((q0blk - (WIN_ - 1)) >> 6) : 0;
  const int teu = (q0blk + 255) >> 6;

  // ---- staging roles (fused fp32 -> bf16), 2 jobs per stager thread ----
  const bool isK = (tid < 256);
  const bool stager = (tid < 512);
  const float *gfA = nullptr, *gfB = nullptr;
  const size_t gstepf = (size_t)64 * H_ * D_;  // fp32 elems per 64-key tile
  int dstA = 0, dstB = 0, vkey = 0, vd0 = 0;
  if (isK) {
    const int c = tid & 7;
    const int r0 = tid >> 3;          // 0..31
    const int r1 = r0 + 32;           // 32..63
    gfA = kf + ((size_t)(b * S_ + r0) * H_ + h) * D_ + c * 8;
    gfB = kf + ((size_t)(b * S_ + r1) * H_ + h) * D_ + c * 8;
    dstA = r0 * 64 + ((c * 8) ^ ((r0 & 7) << 3));
    dstB = r1 * 64 + ((c * 8) ^ ((r1 & 7) << 3));
  } else if (stager) {
    const int u = tid - 256;          // 0..255
    vkey = u & 63;
    vd0 = (u >> 6) * 8;               // 0,8,16,24 ; second job +32
    gfA = vf + ((size_t)(b * S_ + vkey) * H_ + h) * D_ + vd0;
    gfB = gfA + 32;
  }

  auto kpack = [](float4 a, float4 c) {
    union { u16 s[8]; uint4 q; } t;
    t.s[0] = f2bf(a.x); t.s[1] = f2bf(a.y); t.s[2] = f2bf(a.z); t.s[3] = f2bf(a.w);
    t.s[4] = f2bf(c.x); t.s[5] = f2bf(c.y); t.s[6] = f2bf(c.z); t.s[7] = f2bf(c.w);
    return t.q;
  };
  auto vscatter = [&](u16* vb, int d0, float4 a, float4 c) {
    float vals[8] = {a.x, a.y, a.z, a.w, c.x, c.y, c.z, c.w};
#pragma unroll
    for (int i = 0; i < 8; ++i) {
      const int d = d0 + i;
      vb[d * 64 + (vkey ^ ((d & 7) << 3))] = f2bf(vals[i]);
    }
  };

  // ds_read offsets (element units); K/V rows are 64 elems (128B)
  const int ko0 = lj * 64 + ((lg * 8) ^ ((lj & 7) << 3));
  const int ko1 = lj * 64 + ((32 + lg * 8) ^ ((lj & 7) << 3));
  const int po = lj * 40 + lg * 8;   // 80B rows: 16B-aligned b128 reads

  // ---- prologue: stage tile tbu into buf0; prefetch tile tbu+1 ----
  if (stager) {
    float4 a0 = *(const float4*)(gfA + gstepf * tbu);
    float4 b0 = *(const float4*)(gfA + gstepf * tbu + 4);
    float4 a1 = *(const float4*)(gfB + gstepf * tbu);
    float4 b1 = *(const float4*)(gfB + gstepf * tbu + 4);
    if (isK) {
      *(uint4*)(klds0 + dstA) = kpack(a0, b0);
      *(uint4*)(klds0 + dstB) = kpack(a1, b1);
    } else {
      vscatter(vlds0, vd0, a0, b0);
      vscatter(vlds0, vd0 + 32, a1, b1);
    }
  }
  float4 gaA, gbA, gaB, gbB;
  if (stager && tbu < teu) {
    gaA = *(const float4*)(gfA + gstepf * (tbu + 1));
    gbA = *(const float4*)(gfA + gstepf * (tbu + 1) + 4);
    gaB = *(const float4*)(gfB + gstepf * (tbu + 1));
    gbB = *(const float4*)(gfB + gstepf * (tbu + 1) + 4);
  }
  __syncthreads();

  int cur = 0;
  for (int t = tbu; t <= teu; ++t) {
    const u16* K = cur ? klds1 : klds0;
    const u16* V = cur ? vlds1 : vlds0;
#pragma unroll
    for (int s = 0; s < 2; ++s) {
      const int ts = t * 2 + s;
      if (ts >= tbw32 && ts <= tew32) {
        const u16* Kb = K + s * 2048;   // +32 key rows
        bf16x8 k00 = *(const bf16x8*)(Kb + ko0);
        bf16x8 k01 = *(const bf16x8*)(Kb + ko1);
        bf16x8 k10 = *(const bf16x8*)(Kb + ko0 + 1024);
        bf16x8 k11 = *(const bf16x8*)(Kb + ko1 + 1024);

        f32x4 sA = {0.f, 0.f, 0.f, 0.f}, sB = sA;
        sA = MFMA(aq0, k00, sA);
        sA = MFMA(aq1, k01, sA);
        sB = MFMA(aq0, k10, sB);
        sB = MFMA(aq1, k11, sB);

        const bool edge = (ts == tew32) || (wmask && ts == tbw32);
        const int kt = ts * 32;
        u16* ps = &plds[wave][0];
#pragma unroll
        for (int r = 0; r < 4; ++r) {
          float ea = __builtin_amdgcn_exp2f(sA[r]);
          float eb = __builtin_amdgcn_exp2f(sB[r]);
          if (edge) {
            const int qpos = q0w + lg * 4 + r;
            const int kA = kt + lj, kB = kA + 16;
            const bool okA = (kA <= qpos) && (kA > qpos - WIN_);
            const bool okB = (kB <= qpos) && (kB > qpos - WIN_);
            ea = okA ? ea : 0.f;
            eb = okB ? eb : 0.f;
          }
          lacc[r] += ea + eb;
          // truncating f32->bf16 (1 VALU); softmax ratio cancels the bias
          ps[(lg * 4 + r) * 40 + lj] = (u16)(__float_as_uint(ea) >> 16);
          ps[(lg * 4 + r) * 40 + 16 + lj] = (u16)(__float_as_uint(eb) >> 16);
        }
        bf16x8 ap = *(const bf16x8*)(ps + po);

        const int vos = lj * 64 + ((s * 32 + lg * 8) ^ ((lj & 7) << 3));
        bf16x8 v0 = *(const bf16x8*)(V + vos);
        bf16x8 v1 = *(const bf16x8*)(V + vos + 1024);
        bf16x8 v2 = *(const bf16x8*)(V + vos + 2048);
        bf16x8 v3 = *(const bf16x8*)(V + vos + 3072);
        o0 = MFMA(ap, v0, o0);
        o1 = MFMA(ap, v1, o1);
        o2 = MFMA(ap, v2, o2);
        o3 = MFMA(ap, v3, o3);
      }
    }

    // write prefetched (converted) tile t+1 into the other buffer
    if (stager && t < teu) {
      if (isK) {
        u16* dl = cur ? klds0 : klds1;
        *(uint4*)(dl + dstA) = kpack(gaA, gbA);
        *(uint4*)(dl + dstB) = kpack(gaB, gbB);
      } else {
        u16* vb = cur ? vlds0 : vlds1;
        vscatter(vb, vd0, gaA, gbA);
        vscatter(vb, vd0 + 32, gaB, gbB);
      }
    }
    __syncthreads();
    if (stager && t + 1 < teu) {
      gaA = *(const float4*)(gfA + gstepf * (t + 2));
      gbA = *(const float4*)(gfA + gstepf * (t + 2) + 4);
      gaB = *(const float4*)(gfB + gstepf * (t + 2));
      gbB = *(const float4*)(gfB + gstepf * (t + 2) + 4);
    }
    cur ^= 1;
  }

  // ---- epilogue: reduce l over 16 key-columns, normalize, store bf16 ----
#pragma unroll
  for (int r = 0; r < 4; ++r) {
    float l = lacc[r];
    l += __shfl_xor(l, 1);
    l += __shfl_xor(l, 2);
    l += __shfl_xor(l, 4);
    l += __shfl_xor(l, 8);
    const float inv = 1.0f / l;
    const int row = q0w + lg * 4 + r;
    u16* orow = attn + (size_t)(b * S_ + row) * HD_ + h * D_;
    orow[lj] = f2bf(o0[r] * inv);
    orow[16 + lj] = f2bf(o1[r] * inv);
    orow[32 + lj] = f2bf(o2[r] * inv);
    orow[48 + lj] = f2bf(o3[r] * inv);
  }
}

// ---------------------------------------------------------------------------
// out = attn[16384,512](bf16) @ W^T + bias, fp32 out. W read DIRECTLY as
// fp32 and converted in-register (cvt pre-pass eliminated; W is L2-resident
// so the extra read bytes are L2 traffic, VALU conversion free in this
// memory-bound kernel).
// ---------------------------------------------------------------------------
__global__ __launch_bounds__(512) void gemm_kernel(const u16* __restrict__ A,
                                                   const float* __restrict__ Wf,
                                                   const float* __restrict__ bias,
                                                   float* __restrict__ out) {
  const int tid = threadIdx.x;
  const int lane = tid & 63;
  const int wave = tid >> 6;
  const int lg = lane >> 4, lj = lane & 15;
  const int phys = (int)blockIdx.x;
  const int swz = (phys & 7) * 32 + (phys >> 3);
  const int rb = swz >> 1, cb = swz & 1;
  const int wr = wave >> 2, wc = wave & 3;
  const int row0 = rb * 128;
  const int col0 = cb * 256 + wc * 64;

  __shared__ __align__(16) u16 alds[2][128 * 64];

  const int srow = tid >> 3;
  const int skc = tid & 7;
  const u16* ag0 = A + (size_t)(row0 + srow) * HD_ + skc * 8;
  const u16* ag1 = A + (size_t)(row0 + 64 + srow) * HD_ + skc * 8;
  const int dst0 = srow * 64 + ((skc * 8) ^ ((srow & 7) << 3));
  const int dst1 = (64 + srow) * 64 + ((skc * 8) ^ ((srow & 7) << 3));

  f32x4 acc[4][4];
#pragma unroll
  for (int fr = 0; fr < 4; ++fr)
#pragma unroll
    for (int fc = 0; fc < 4; ++fc) acc[fr][fc] = (f32x4){0.f, 0.f, 0.f, 0.f};

  *(uint4*)(&alds[0][dst0]) = *(const uint4*)ag0;
  *(uint4*)(&alds[0][dst1]) = *(const uint4*)ag1;
  __syncthreads();

  uint4 pre0, pre1;
  int cur = 0;
  for (int kt = 0; kt < HD_; kt += 64) {
    if (kt + 64 < HD_) {
      pre0 = *(const uint4*)(ag0 + kt + 64);
      pre1 = *(const uint4*)(ag1 + kt + 64);
    }
    const u16* Abuf = alds[cur];
#pragma unroll
    for (int ks = 0; ks < 2; ++ks) {
      bf16x8 fa[4], fb[4];
#pragma unroll
      for (int fr = 0; fr < 4; ++fr) {
        const int rr = wr * 64 + fr * 16 + lj;
        fa[fr] = *(const bf16x8*)(Abuf + rr * 64 + ((ks * 32 + lg * 8) ^ ((lj & 7) << 3)));
      }
#pragma unroll
      for (int fc = 0; fc < 4; ++fc)
        fb[fc] = cvt8(Wf + (size_t)(col0 + fc * 16 + lj) * HD_ + kt + ks * 32 + lg * 8);
#pragma unroll
      for (int fr = 0; fr < 4; ++fr)
#pragma unroll
        for (int fc = 0; fc < 4; ++fc)
          acc[fr][fc] = MFMA(fa[fr], fb[fc], acc[fr][fc]);
    }
    if (kt + 64 < HD_) {
      u16* db = alds[cur ^ 1];
      *(uint4*)(&db[dst0]) = pre0;
      *(uint4*)(&db[dst1]) = pre1;
    }
    __syncthreads();
    cur ^= 1;
  }

#pragma unroll
  for (int fc = 0; fc < 4; ++fc) {
    const float bv = bias[col0 + fc * 16 + lj];
#pragma unroll
    for (int fr = 0; fr < 4; ++fr) {
#pragma unroll
      for (int r = 0; r < 4; ++r) {
        const int row = row0 + wr * 64 + fr * 16 + lg * 4 + r;
        out[(size_t)row * HD_ + col0 + fc * 16 + lj] = acc[fr][fc][r] + bv;
      }
    }
  }
}

// ---------------------------------------------------------------------------
extern "C" void kernel_launch(void* const* d_in, const int* in_sizes, int n_in,
                              void* d_out, int out_size, void* d_ws, size_t ws_size,
                              hipStream_t stream) {
  const float* q = (const float*)d_in[0];
  const float* k = (const float*)d_in[1];
  const float* v = (const float*)d_in[2];
  const float* w = (const float*)d_in[3];
  const float* bias = (const float*)d_in[4];
  float* out = (float*)d_out;

  u16* attn = (u16*)d_ws;                    // 16,777,216 B : attn bf16 [B*S, 512]

  // fused attention: B*H*(S/256) = 512 blocks x 1024 threads, BK=64 tiles
  hipLaunchKernelGGL(attn_kernel, dim3(512), dim3(1024), 0, stream, q, k, v, attn);
  // out-projection (W converted in-register): 256 blocks x 512 threads
  hipLaunchKernelGGL(gemm_kernel, dim3(256), dim3(512), 0, stream, attn, w, bias, out);
}

// Round 28
// 83.817 us; speedup vs baseline: 1.1208x; 1.1208x over previous
//
#include <hip/hip_runtime.h>

#define B_ 2
#define S_ 8192
#define H_ 8
#define D_ 64
#define HD_ 512
#define WIN_ 512

typedef __bf16 bf16x8 __attribute__((ext_vector_type(8)));
typedef float f32x4 __attribute__((ext_vector_type(4)));
typedef unsigned short u16;
typedef unsigned int u32;

__device__ __forceinline__ u16 f2bf(float f) {
  u32 u = __float_as_uint(f);
  u += 0x7FFFu + ((u >> 16) & 1u);
  return (u16)(u >> 16);
}

__device__ __forceinline__ bf16x8 cvt8s(const float* p, float s) {
  const float4 a = *(const float4*)p;
  const float4 b = *(const float4*)(p + 4);
  union { u16 s[8]; bf16x8 v; } r;
  r.s[0] = f2bf(a.x * s); r.s[1] = f2bf(a.y * s); r.s[2] = f2bf(a.z * s); r.s[3] = f2bf(a.w * s);
  r.s[4] = f2bf(b.x * s); r.s[5] = f2bf(b.y * s); r.s[6] = f2bf(b.z * s); r.s[7] = f2bf(b.w * s);
  return r.v;
}

#define MFMA(a, b, c) __builtin_amdgcn_mfma_f32_16x16x32_bf16(a, b, c, 0, 0, 0)

// ---------------------------------------------------------------------------
// generic fp32 -> bf16 conversion (vectorized x4) — used only for W
// ---------------------------------------------------------------------------
__global__ __launch_bounds__(256) void cvt_kernel(const float* __restrict__ in,
                                                  u16* __restrict__ out, int n4) {
  int i = blockIdx.x * 256 + threadIdx.x;
  if (i < n4) {
    float4 f = ((const float4*)in)[i];
    ushort4 r;
    r.x = f2bf(f.x); r.y = f2bf(f.y); r.z = f2bf(f.z); r.w = f2bf(f.w);
    ((ushort4*)out)[i] = r;
  }
}

// ---------------------------------------------------------------------------
// Block-cooperative sliding-window flash attention, fused fp32 staging,
// BK=64 key tiles (12 barrier generations). 1024 threads = 16 waves x 16
// queries; block owns 256 q; 512 blocks = 2 resident blocks/CU. Each tile:
// one barrier, two 32-key subtiles computed back-to-back from the same
// staged buffers. Staging: tid<256 K (2 row-chunks), tid in [256,512) V
// (2 d-chunks, on-the-fly transpose). K [64k][64d], V [64d][64k], both
// with (^ (row&7)<<3) 16B-slot swizzle. P rows 40 elem. Fixed-ref exp2
// softmax; truncating P->bf16. [BEST VERIFIED: attn ~72us, total ~84us]
// ---------------------------------------------------------------------------
__global__ __launch_bounds__(1024, 4) void attn_kernel(const float* __restrict__ q,
                                                       const float* __restrict__ kf,
                                                       const float* __restrict__ vf,
                                                       u16* __restrict__ attn) {
  const int tid = threadIdx.x;
  const int lane = tid & 63;
  const int wave = tid >> 6;   // 0..15
  const int lg = lane >> 4;    // 0..3
  const int lj = lane & 15;    // 0..15
  // XCD swizzle: 512 blocks, 8 XCDs, 64-block contiguous chunks (bijective)
  const int bid = (int)blockIdx.x;
  const int swz = (bid & 7) * 64 + (bid >> 3);
  const int qc = swz & 31;     // S_/256 = 32 query chunks
  const int bh = swz >> 5;
  const int b = bh >> 3, h = bh & 7;
  const int q0blk = qc * 256;
  const int q0w = q0blk + wave * 16;

  __shared__ __align__(16) u16 klds0[64 * 64], klds1[64 * 64];  // 8KB each
  __shared__ __align__(16) u16 vlds0[64 * 64], vlds1[64 * 64];  // 8KB each
  __shared__ __align__(16) u16 plds[16][16 * 40];               // 1280B/wave

  const float qscale = 0.125f * 1.4426950408889634f;
  bf16x8 aq0, aq1;
  {
    const float* qrow = q + ((size_t)(b * S_ + q0w + lj) * H_ + h) * D_;
    aq0 = cvt8s(qrow + lg * 8, qscale);
    aq1 = cvt8s(qrow + 32 + lg * 8, qscale);
  }

  f32x4 o0 = {0.f, 0.f, 0.f, 0.f}, o1 = o0, o2 = o0, o3 = o0;
  float lacc[4] = {0.f, 0.f, 0.f, 0.f};

  // per-wave valid range in 32-key SUBTILE units
  const int tbw32 = (q0w >= WIN_) ? ((q0w - (WIN_ - 1)) >> 5) : 0;
  const int tew32 = (q0w + 15) >> 5;
  const bool wmask = (q0w >= WIN_);
  // block union range in 64-key TILE units
  const int tbu = (q0blk >= WIN_) ? ((q0blk - (WIN_ - 1)) >> 6) : 0;
  const int teu = (q0blk + 255) >> 6;

  // ---- staging roles (fused fp32 -> bf16), 2 jobs per stager thread ----
  const bool isK = (tid < 256);
  const bool stager = (tid < 512);
  const float *gfA = nullptr, *gfB = nullptr;
  const size_t gstepf = (size_t)64 * H_ * D_;  // fp32 elems per 64-key tile
  int dstA = 0, dstB = 0, vkey = 0, vd0 = 0;
  if (isK) {
    const int c = tid & 7;
    const int r0 = tid >> 3;          // 0..31
    const int r1 = r0 + 32;           // 32..63
    gfA = kf + ((size_t)(b * S_ + r0) * H_ + h) * D_ + c * 8;
    gfB = kf + ((size_t)(b * S_ + r1) * H_ + h) * D_ + c * 8;
    dstA = r0 * 64 + ((c * 8) ^ ((r0 & 7) << 3));
    dstB = r1 * 64 + ((c * 8) ^ ((r1 & 7) << 3));
  } else if (stager) {
    const int u = tid - 256;          // 0..255
    vkey = u & 63;
    vd0 = (u >> 6) * 8;               // 0,8,16,24 ; second job +32
    gfA = vf + ((size_t)(b * S_ + vkey) * H_ + h) * D_ + vd0;
    gfB = gfA + 32;
  }

  auto kpack = [](float4 a, float4 c) {
    union { u16 s[8]; uint4 q; } t;
    t.s[0] = f2bf(a.x); t.s[1] = f2bf(a.y); t.s[2] = f2bf(a.z); t.s[3] = f2bf(a.w);
    t.s[4] = f2bf(c.x); t.s[5] = f2bf(c.y); t.s[6] = f2bf(c.z); t.s[7] = f2bf(c.w);
    return t.q;
  };
  auto vscatter = [&](u16* vb, int d0, float4 a, float4 c) {
    float vals[8] = {a.x, a.y, a.z, a.w, c.x, c.y, c.z, c.w};
#pragma unroll
    for (int i = 0; i < 8; ++i) {
      const int d = d0 + i;
      vb[d * 64 + (vkey ^ ((d & 7) << 3))] = f2bf(vals[i]);
    }
  };

  // ds_read offsets (element units); K/V rows are 64 elems (128B)
  const int ko0 = lj * 64 + ((lg * 8) ^ ((lj & 7) << 3));
  const int ko1 = lj * 64 + ((32 + lg * 8) ^ ((lj & 7) << 3));
  const int po = lj * 40 + lg * 8;   // 80B rows: 16B-aligned b128 reads

  // ---- prologue: stage tile tbu into buf0; prefetch tile tbu+1 ----
  if (stager) {
    float4 a0 = *(const float4*)(gfA + gstepf * tbu);
    float4 b0 = *(const float4*)(gfA + gstepf * tbu + 4);
    float4 a1 = *(const float4*)(gfB + gstepf * tbu);
    float4 b1 = *(const float4*)(gfB + gstepf * tbu + 4);
    if (isK) {
      *(uint4*)(klds0 + dstA) = kpack(a0, b0);
      *(uint4*)(klds0 + dstB) = kpack(a1, b1);
    } else {
      vscatter(vlds0, vd0, a0, b0);
      vscatter(vlds0, vd0 + 32, a1, b1);
    }
  }
  float4 gaA, gbA, gaB, gbB;
  if (stager && tbu < teu) {
    gaA = *(const float4*)(gfA + gstepf * (tbu + 1));
    gbA = *(const float4*)(gfA + gstepf * (tbu + 1) + 4);
    gaB = *(const float4*)(gfB + gstepf * (tbu + 1));
    gbB = *(const float4*)(gfB + gstepf * (tbu + 1) + 4);
  }
  __syncthreads();

  int cur = 0;
  for (int t = tbu; t <= teu; ++t) {
    const u16* K = cur ? klds1 : klds0;
    const u16* V = cur ? vlds1 : vlds0;
#pragma unroll
    for (int s = 0; s < 2; ++s) {
      const int ts = t * 2 + s;
      if (ts >= tbw32 && ts <= tew32) {
        const u16* Kb = K + s * 2048;   // +32 key rows
        bf16x8 k00 = *(const bf16x8*)(Kb + ko0);
        bf16x8 k01 = *(const bf16x8*)(Kb + ko1);
        bf16x8 k10 = *(const bf16x8*)(Kb + ko0 + 1024);
        bf16x8 k11 = *(const bf16x8*)(Kb + ko1 + 1024);

        f32x4 sA = {0.f, 0.f, 0.f, 0.f}, sB = sA;
        sA = MFMA(aq0, k00, sA);
        sA = MFMA(aq1, k01, sA);
        sB = MFMA(aq0, k10, sB);
        sB = MFMA(aq1, k11, sB);

        const bool edge = (ts == tew32) || (wmask && ts == tbw32);
        const int kt = ts * 32;
        u16* ps = &plds[wave][0];
#pragma unroll
        for (int r = 0; r < 4; ++r) {
          float ea = __builtin_amdgcn_exp2f(sA[r]);
          float eb = __builtin_amdgcn_exp2f(sB[r]);
          if (edge) {
            const int qpos = q0w + lg * 4 + r;
            const int kA = kt + lj, kB = kA + 16;
            const bool okA = (kA <= qpos) && (kA > qpos - WIN_);
            const bool okB = (kB <= qpos) && (kB > qpos - WIN_);
            ea = okA ? ea : 0.f;
            eb = okB ? eb : 0.f;
          }
          lacc[r] += ea + eb;
          // truncating f32->bf16 (1 VALU); softmax ratio cancels the bias
          ps[(lg * 4 + r) * 40 + lj] = (u16)(__float_as_uint(ea) >> 16);
          ps[(lg * 4 + r) * 40 + 16 + lj] = (u16)(__float_as_uint(eb) >> 16);
        }
        bf16x8 ap = *(const bf16x8*)(ps + po);

        const int vos = lj * 64 + ((s * 32 + lg * 8) ^ ((lj & 7) << 3));
        bf16x8 v0 = *(const bf16x8*)(V + vos);
        bf16x8 v1 = *(const bf16x8*)(V + vos + 1024);
        bf16x8 v2 = *(const bf16x8*)(V + vos + 2048);
        bf16x8 v3 = *(const bf16x8*)(V + vos + 3072);
        o0 = MFMA(ap, v0, o0);
        o1 = MFMA(ap, v1, o1);
        o2 = MFMA(ap, v2, o2);
        o3 = MFMA(ap, v3, o3);
      }
    }

    // write prefetched (converted) tile t+1 into the other buffer
    if (stager && t < teu) {
      if (isK) {
        u16* dl = cur ? klds0 : klds1;
        *(uint4*)(dl + dstA) = kpack(gaA, gbA);
        *(uint4*)(dl + dstB) = kpack(gaB, gbB);
      } else {
        u16* vb = cur ? vlds0 : vlds1;
        vscatter(vb, vd0, gaA, gbA);
        vscatter(vb, vd0 + 32, gaB, gbB);
      }
    }
    __syncthreads();
    if (stager && t + 1 < teu) {
      gaA = *(const float4*)(gfA + gstepf * (t + 2));
      gbA = *(const float4*)(gfA + gstepf * (t + 2) + 4);
      gaB = *(const float4*)(gfB + gstepf * (t + 2));
      gbB = *(const float4*)(gfB + gstepf * (t + 2) + 4);
    }
    cur ^= 1;
  }

  // ---- epilogue: reduce l over 16 key-columns, normalize, store bf16 ----
#pragma unroll
  for (int r = 0; r < 4; ++r) {
    float l = lacc[r];
    l += __shfl_xor(l, 1);
    l += __shfl_xor(l, 2);
    l += __shfl_xor(l, 4);
    l += __shfl_xor(l, 8);
    const float inv = 1.0f / l;
    const int row = q0w + lg * 4 + r;
    u16* orow = attn + (size_t)(b * S_ + row) * HD_ + h * D_;
    orow[lj] = f2bf(o0[r] * inv);
    orow[16 + lj] = f2bf(o1[r] * inv);
    orow[32 + lj] = f2bf(o2[r] * inv);
    orow[48 + lj] = f2bf(o3[r] * inv);
  }
}

// ---------------------------------------------------------------------------
// out = attn[16384,512](bf16) @ W^T + bias, fp32 out. W pre-converted to
// bf16 by cvt_kernel (in-register fp32 conversion regressed in R27: doubled
// VMEM + VALU in the inner loop cost ~12us).
// ---------------------------------------------------------------------------
__global__ __launch_bounds__(512) void gemm_kernel(const u16* __restrict__ A,
                                                   const u16* __restrict__ Wb,
                                                   const float* __restrict__ bias,
                                                   float* __restrict__ out) {
  const int tid = threadIdx.x;
  const int lane = tid & 63;
  const int wave = tid >> 6;
  const int lg = lane >> 4, lj = lane & 15;
  const int phys = (int)blockIdx.x;
  const int swz = (phys & 7) * 32 + (phys >> 3);
  const int rb = swz >> 1, cb = swz & 1;
  const int wr = wave >> 2, wc = wave & 3;
  const int row0 = rb * 128;
  const int col0 = cb * 256 + wc * 64;

  __shared__ __align__(16) u16 alds[2][128 * 64];

  const int srow = tid >> 3;
  const int skc = tid & 7;
  const u16* ag0 = A + (size_t)(row0 + srow) * HD_ + skc * 8;
  const u16* ag1 = A + (size_t)(row0 + 64 + srow) * HD_ + skc * 8;
  const int dst0 = srow * 64 + ((skc * 8) ^ ((srow & 7) << 3));
  const int dst1 = (64 + srow) * 64 + ((skc * 8) ^ ((srow & 7) << 3));

  f32x4 acc[4][4];
#pragma unroll
  for (int fr = 0; fr < 4; ++fr)
#pragma unroll
    for (int fc = 0; fc < 4; ++fc) acc[fr][fc] = (f32x4){0.f, 0.f, 0.f, 0.f};

  *(uint4*)(&alds[0][dst0]) = *(const uint4*)ag0;
  *(uint4*)(&alds[0][dst1]) = *(const uint4*)ag1;
  __syncthreads();

  uint4 pre0, pre1;
  int cur = 0;
  for (int kt = 0; kt < HD_; kt += 64) {
    if (kt + 64 < HD_) {
      pre0 = *(const uint4*)(ag0 + kt + 64);
      pre1 = *(const uint4*)(ag1 + kt + 64);
    }
    const u16* Abuf = alds[cur];
#pragma unroll
    for (int ks = 0; ks < 2; ++ks) {
      bf16x8 fa[4], fb[4];
#pragma unroll
      for (int fr = 0; fr < 4; ++fr) {
        const int rr = wr * 64 + fr * 16 + lj;
        fa[fr] = *(const bf16x8*)(Abuf + rr * 64 + ((ks * 32 + lg * 8) ^ ((lj & 7) << 3)));
      }
#pragma unroll
      for (int fc = 0; fc < 4; ++fc)
        fb[fc] = *(const bf16x8*)(Wb + (size_t)(col0 + fc * 16 + lj) * HD_ + kt + ks * 32 + lg * 8);
#pragma unroll
      for (int fr = 0; fr < 4; ++fr)
#pragma unroll
        for (int fc = 0; fc < 4; ++fc)
          acc[fr][fc] = MFMA(fa[fr], fb[fc], acc[fr][fc]);
    }
    if (kt + 64 < HD_) {
      u16* db = alds[cur ^ 1];
      *(uint4*)(&db[dst0]) = pre0;
      *(uint4*)(&db[dst1]) = pre1;
    }
    __syncthreads();
    cur ^= 1;
  }

#pragma unroll
  for (int fc = 0; fc < 4; ++fc) {
    const float bv = bias[col0 + fc * 16 + lj];
#pragma unroll
    for (int fr = 0; fr < 4; ++fr) {
#pragma unroll
      for (int r = 0; r < 4; ++r) {
        const int row = row0 + wr * 64 + fr * 16 + lg * 4 + r;
        out[(size_t)row * HD_ + col0 + fc * 16 + lj] = acc[fr][fc][r] + bv;
      }
    }
  }
}

// ---------------------------------------------------------------------------
extern "C" void kernel_launch(void* const* d_in, const int* in_sizes, int n_in,
                              void* d_out, int out_size, void* d_ws, size_t ws_size,
                              hipStream_t stream) {
  const float* q = (const float*)d_in[0];
  const float* k = (const float*)d_in[1];
  const float* v = (const float*)d_in[2];
  const float* w = (const float*)d_in[3];
  const float* bias = (const float*)d_in[4];
  float* out = (float*)d_out;

  char* ws = (char*)d_ws;
  u16* attn = (u16*)ws;                      // 16,777,216 B : attn bf16 [B*S, 512]
  u16* wb = (u16*)(ws + 16777216);           //    524,288 B : W bf16 [512,512]

  // W convert: 262,144 / 4 = 65,536 threads
  hipLaunchKernelGGL(cvt_kernel, dim3(256), dim3(256), 0, stream, w, wb, 65536);
  // fused attention: B*H*(S/256) = 512 blocks x 1024 threads, BK=64 tiles
  hipLaunchKernelGGL(attn_kernel, dim3(512), dim3(1024), 0, stream, q, k, v, attn);
  // out-projection: 128 row-blocks x 2 col-blocks = 256 blocks, 512 threads
  hipLaunchKernelGGL(gemm_kernel, dim3(256), dim3(512), 0, stream, attn, wb, bias, out);
}